// Round 5
// baseline (154.576 us; speedup 1.0000x reference)
//
#include <hip/hip_runtime.h>
#include <hip/hip_bf16.h>
#include <math.h>

#define BB 4
#define VV 1024
#define HH 128
#define H2 64
#define EE 523776               // V*(V-1)/2
#define BE (BB * EE)            // 2095104
#define TPB (EE / 16)           // 32736 tiles per batch (even)
#define NTILES (BE / 16)        // 130944
#define NPAIR (NTILES / 2)      // 65472
#define NTHR 256
#define NBLK 1024
#define STRIDE (NBLK * 4)       // wave stride over pairs

typedef __attribute__((ext_vector_type(8))) short bf16x8;
typedef __attribute__((ext_vector_type(4))) float f32x4;

// Opaque-value pin: compiler cannot rematerialize x after this, so it must
// stay VGPR-resident for its whole live range (R4's VGPR=108 < 128-persistent
// proved the compiler was re-loading weights from memory inside the loop).
#define KEEPV(x) asm volatile("" : "+v"(*(f32x4*)&(x)))
#define KEEPF(x) asm volatile("" : "+v"(x))

__device__ __forceinline__ short f2bf(float f) {
    __hip_bfloat16 h = __float2bfloat16(f);
    return *reinterpret_cast<short*>(&h);
}

struct Pre {
    float f[2][6];
    int   iv[2], jv[2];
};

// decode pair-tile pt -> (i,j) per edge slot, and ISSUE vertex loads (u==0).
__device__ __forceinline__ void stage(int pt, int col, int u,
                                      const float* __restrict__ vertices,
                                      Pre& P) {
    const int tt0 = pt * 2;
    const int b   = tt0 / TPB;
    const int e00 = (tt0 - b * TPB) * 16;
#pragma unroll
    for (int s = 0; s < 2; ++s) {
        const int e  = e00 + s * 16 + col;
        const int rr = EE - 1 - e;
        const float sq = sqrtf((float)(8 * rr + 1));   // exact: 8rr+1 < 2^23
        int m = (int)(0.5f * (sq - 1.0f));
        if ((m + 1) * (m + 2) / 2 <= rr) ++m;          // one-step ulp fixups
        if (m * (m + 1) / 2 > rr) --m;
        const int pp = rr - m * (m + 1) / 2;
        P.iv[s] = VV - 2 - m;
        P.jv[s] = VV - 1 - pp;
        if (u == 0) {
            const float* pvi = vertices + (b * VV + P.iv[s]) * 3;
            const float* pvj = vertices + (b * VV + P.jv[s]) * 3;
            P.f[s][0] = pvi[0]; P.f[s][1] = pvi[1]; P.f[s][2] = pvi[2];
            P.f[s][3] = pvj[0]; P.f[s][4] = pvj[1]; P.f[s][5] = pvj[2];
        }
    }
}

// ---------------------------------------------------------------------------
// Round 5: R4 + (a) weight fragments force-pinned in VGPRs via opaque asm,
// (b) vertex gather software-pipelined one iteration ahead (T14: issue-early,
// use-late), 2-tile ILP retained. No LDS, no barriers.
// ---------------------------------------------------------------------------
__global__ __launch_bounds__(NTHR, 2) void edge_mlp_mfma4(
    const float* __restrict__ vertices,  // [4,1024,3]
    const float* __restrict__ W1,        // [6,128]
    const float* __restrict__ b1,        // [128]
    const float* __restrict__ W2,        // [128,64]
    const float* __restrict__ b2,        // [64]
    const float* __restrict__ W3,        // [64]
    const float* __restrict__ b3,        // [1]
    float* __restrict__ out)             // [BE probs][2*EE indices-as-float]
{
    const int lane = threadIdx.x & 63;
    const int col  = lane & 15;          // edge slot (N dim everywhere)
    const int u    = lane >> 4;
    const int wid  = threadIdx.x >> 6;

    const f32x4 zero4 = {0.f, 0.f, 0.f, 0.f};

    // ---- persistent weight fragments ----
    // L1: A1[p][q][r] = W1pad[k=8u+r][h], h = 32p + 8*(col>>2) + 4q + (col&3)
    // (A-row permutation chosen so L1's C/D layout IS L2's B-frag layout)
    bf16x8 A1[4][2];
#pragma unroll
    for (int p = 0; p < 4; ++p)
#pragma unroll
        for (int q = 0; q < 2; ++q) {
            const int h = 32 * p + 8 * (col >> 2) + 4 * q + (col & 3);
#pragma unroll
            for (int r = 0; r < 8; ++r) {
                const int k = 8 * u + r;
                float w = 0.0f;
                if (k < 6)       w = W1[k * HH + h];
                else if (k == 6) w = b1[h];
                A1[p][q][r] = f2bf(w);
            }
        }

    // L2: A2[mt][p][r] = W2[h=32p+8u+r][n2=16mt+col]
    bf16x8 A2[4][4];
#pragma unroll
    for (int mt = 0; mt < 4; ++mt)
#pragma unroll
        for (int p = 0; p < 4; ++p) {
            const int n2 = 16 * mt + col;
#pragma unroll
            for (int r = 0; r < 8; ++r) {
                const int h = 32 * p + 8 * u + r;
                A2[mt][p][r] = f2bf(W2[h * H2 + n2]);
            }
        }

    // epilogue constants; b2 enters as the L2 accumulator init
    f32x4 cinit[4];
    float w3c[16];
#pragma unroll
    for (int mt = 0; mt < 4; ++mt)
#pragma unroll
        for (int q = 0; q < 4; ++q) {
            const int n2 = 16 * mt + 4 * u + q;
            cinit[mt][q]    = b2[n2];
            w3c[mt * 4 + q] = W3[n2];
        }
    const float b3v = b3[0];

    // ---- pin everything persistent ----
#pragma unroll
    for (int p = 0; p < 4; ++p) { KEEPV(A1[p][0]); KEEPV(A1[p][1]); }
#pragma unroll
    for (int mt = 0; mt < 4; ++mt)
#pragma unroll
        for (int p = 0; p < 4; ++p) KEEPV(A2[mt][p]);
#pragma unroll
    for (int mt = 0; mt < 4; ++mt) KEEPV(cinit[mt]);
#pragma unroll
    for (int q = 0; q < 16; ++q) KEEPF(w3c[q]);

    const int gw = blockIdx.x * 4 + wid;

    Pre cur, nxt;
    stage(gw, col, u, vertices, cur);    // gw < 4096 < NPAIR always

    for (int pt = gw; pt < NPAIR; pt += STRIDE) {
        const int ptn = pt + STRIDE;
        if (ptn < NPAIR) stage(ptn, col, u, vertices, nxt);  // issue-early

        const int tt0 = pt * 2;
        const int b   = tt0 / TPB;

        // ---- build feature B-frags from prefetched floats ----
        bf16x8 bfv[2];
#pragma unroll
        for (int s = 0; s < 2; ++s) {
            bf16x8 bf = {0, 0, 0, 0, 0, 0, 0, 0};
            if (u == 0) {
                bf[0] = f2bf(cur.f[s][0]); bf[1] = f2bf(cur.f[s][1]);
                bf[2] = f2bf(cur.f[s][2]); bf[3] = f2bf(cur.f[s][3]);
                bf[4] = f2bf(cur.f[s][4]); bf[5] = f2bf(cur.f[s][5]);
                bf[6] = f2bf(1.0f);                    // k=6 carries b1
            }
            bfv[s] = bf;
        }

        f32x4 d2[2][4];
#pragma unroll
        for (int s = 0; s < 2; ++s)
#pragma unroll
            for (int mt = 0; mt < 4; ++mt) d2[s][mt] = cinit[mt];

        // ---- fused L1 -> relu/pack -> L2, both tiles interleaved ----
#pragma unroll
        for (int p = 0; p < 4; ++p) {
#pragma unroll
            for (int s = 0; s < 2; ++s) {
                f32x4 dA = __builtin_amdgcn_mfma_f32_16x16x32_bf16(A1[p][0], bfv[s], zero4, 0, 0, 0);
                f32x4 dB = __builtin_amdgcn_mfma_f32_16x16x32_bf16(A1[p][1], bfv[s], zero4, 0, 0, 0);
                bf16x8 Bh;
                Bh[0] = f2bf(fmaxf(dA[0], 0.f)); Bh[1] = f2bf(fmaxf(dA[1], 0.f));
                Bh[2] = f2bf(fmaxf(dA[2], 0.f)); Bh[3] = f2bf(fmaxf(dA[3], 0.f));
                Bh[4] = f2bf(fmaxf(dB[0], 0.f)); Bh[5] = f2bf(fmaxf(dB[1], 0.f));
                Bh[6] = f2bf(fmaxf(dB[2], 0.f)); Bh[7] = f2bf(fmaxf(dB[3], 0.f));
                d2[s][0] = __builtin_amdgcn_mfma_f32_16x16x32_bf16(A2[0][p], Bh, d2[s][0], 0, 0, 0);
                d2[s][1] = __builtin_amdgcn_mfma_f32_16x16x32_bf16(A2[1][p], Bh, d2[s][1], 0, 0, 0);
                d2[s][2] = __builtin_amdgcn_mfma_f32_16x16x32_bf16(A2[2][p], Bh, d2[s][2], 0, 0, 0);
                d2[s][3] = __builtin_amdgcn_mfma_f32_16x16x32_bf16(A2[3][p], Bh, d2[s][3], 0, 0, 0);
            }
        }

        // ---- layer 3 + sigmoid + store ----
#pragma unroll
        for (int s = 0; s < 2; ++s) {
            float acc = 0.f;
#pragma unroll
            for (int mt = 0; mt < 4; ++mt)
#pragma unroll
                for (int q = 0; q < 4; ++q)
                    acc = fmaf(fmaxf(d2[s][mt][q], 0.f), w3c[mt * 4 + q], acc);

            acc += __shfl_xor(acc, 16);
            acc += __shfl_xor(acc, 32);

            if (u == 0) {
                const float x = acc + b3v;
                const float prob = __builtin_amdgcn_rcpf(1.0f + __expf(-x));
                out[(tt0 + s) * 16 + col] = prob;
                if (b == 0) {
                    const int e = (tt0 - b * TPB) * 16 + s * 16 + col;
                    *(float2*)(&out[BE + 2 * e]) =
                        make_float2((float)cur.iv[s], (float)cur.jv[s]);
                }
            }
        }

        cur = nxt;
    }
}

extern "C" void kernel_launch(void* const* d_in, const int* in_sizes, int n_in,
                              void* d_out, int out_size, void* d_ws, size_t ws_size,
                              hipStream_t stream) {
    const float* vertices = (const float*)d_in[0];
    const float* W1 = (const float*)d_in[1];
    const float* b1 = (const float*)d_in[2];
    const float* W2 = (const float*)d_in[3];
    const float* b2 = (const float*)d_in[4];
    const float* W3 = (const float*)d_in[5];
    const float* b3 = (const float*)d_in[6];
    float* out = (float*)d_out;

    edge_mlp_mfma4<<<NBLK, NTHR, 0, stream>>>(vertices, W1, b1, W2, b2, W3, b3, out);
}

// Round 6
// 150.543 us; speedup vs baseline: 1.0268x; 1.0268x over previous
//
#include <hip/hip_runtime.h>
#include <hip/hip_bf16.h>
#include <math.h>

#define BB 4
#define VV 1024
#define HH 128
#define H2 64
#define EE 523776               // V*(V-1)/2
#define BE (BB * EE)            // 2095104
#define TPB (EE / 16)           // 32736 tiles per batch (even)
#define NTILES (BE / 16)        // 130944
#define NPAIR (NTILES / 2)      // 65472
#define NTHR 256
#define NBLK 1024
#define STRIDE (NBLK * 4)       // wave stride over pairs

typedef __attribute__((ext_vector_type(8))) short bf16x8;
typedef __attribute__((ext_vector_type(4))) float f32x4;
typedef __attribute__((ext_vector_type(4))) unsigned u32x4;

#define KEEPV(x) asm volatile("" : "+v"(*(f32x4*)&(x)))
#define KEEPF(x) asm volatile("" : "+v"(x))

// RNE convert — used only OUTSIDE the hot loop (weight fragments).
__device__ __forceinline__ short f2bf(float f) {
    __hip_bfloat16 h = __float2bfloat16(f);
    return *reinterpret_cast<short*>(&h);
}

// ONE v_perm_b32: pack two f32 into bf16x2 by truncation (lo -> low half).
// temp = {src0(hi) : src1(lo)}; sel 0x07060302 = [hi.b3,hi.b2,lo.b3,lo.b2].
__device__ __forceinline__ unsigned pkbf(float lo, float hi) {
    return __builtin_amdgcn_perm(__float_as_uint(hi), __float_as_uint(lo),
                                 0x07060302u);
}

// relu + truncation-pack 8 f32 -> bf16x8: 8 fmax + 4 perm.
__device__ __forceinline__ bf16x8 relu_pack(f32x4 a, f32x4 b) {
    u32x4 r;
    r[0] = pkbf(fmaxf(a[0], 0.f), fmaxf(a[1], 0.f));
    r[1] = pkbf(fmaxf(a[2], 0.f), fmaxf(a[3], 0.f));
    r[2] = pkbf(fmaxf(b[0], 0.f), fmaxf(b[1], 0.f));
    r[3] = pkbf(fmaxf(b[2], 0.f), fmaxf(b[3], 0.f));
    return __builtin_bit_cast(bf16x8, r);
}

struct Pre {
    float f[2][6];
    int   iv[2], jv[2];
};

// decode pair-tile pt -> (i,j) per edge slot and load vertex floats.
// Loads run on ALL lanes (u-groups share col -> same addresses, cache-hit).
__device__ __forceinline__ void stage(int pt, int col,
                                      const float* __restrict__ vertices,
                                      Pre& P) {
    const int tt0 = pt * 2;
    const int b   = tt0 / TPB;
    const int e00 = (tt0 - b * TPB) * 16;
#pragma unroll
    for (int s = 0; s < 2; ++s) {
        const int e  = e00 + s * 16 + col;
        const int rr = EE - 1 - e;
        const float sq = sqrtf((float)(8 * rr + 1));   // exact: 8rr+1 < 2^23
        int m = (int)(0.5f * (sq - 1.0f));
        if ((m + 1) * (m + 2) / 2 <= rr) ++m;          // one-step ulp fixups
        if (m * (m + 1) / 2 > rr) --m;
        const int pp = rr - m * (m + 1) / 2;
        P.iv[s] = VV - 2 - m;
        P.jv[s] = VV - 1 - pp;
        const float* pvi = vertices + (b * VV + P.iv[s]) * 3;
        const float* pvj = vertices + (b * VV + P.jv[s]) * 3;
        P.f[s][0] = pvi[0]; P.f[s][1] = pvi[1]; P.f[s][2] = pvi[2];
        P.f[s][3] = pvj[0]; P.f[s][4] = pvj[1]; P.f[s][5] = pvj[2];
    }
}

// ---------------------------------------------------------------------------
// Round 6: R5 structure, VALU fat removed. All in-loop f32->bf16 conversions
// are 1-instr v_perm truncation packs (HIP's __float2bfloat16 RNE sequence is
// ~5 VALU each; 76 of them/pair was ~40% of all VALU issue). b2 folded as the
// C-in of the p=0 L2 MFMA (kills d2-init movs). Feature frag = 3 perms + 4
// cndmask. Same fused L1->L2 register layout, 2-tile ILP, prefetch.
// ---------------------------------------------------------------------------
__global__ __launch_bounds__(NTHR, 2) void edge_mlp_mfma5(
    const float* __restrict__ vertices,  // [4,1024,3]
    const float* __restrict__ W1,        // [6,128]
    const float* __restrict__ b1,        // [128]
    const float* __restrict__ W2,        // [128,64]
    const float* __restrict__ b2,        // [64]
    const float* __restrict__ W3,        // [64]
    const float* __restrict__ b3,        // [1]
    float* __restrict__ out)             // [BE probs][2*EE indices-as-float]
{
    const int lane = threadIdx.x & 63;
    const int col  = lane & 15;          // edge slot (N dim everywhere)
    const int u    = lane >> 4;
    const int wid  = threadIdx.x >> 6;

    const f32x4 zero4 = {0.f, 0.f, 0.f, 0.f};

    // ---- persistent weight fragments ----
    // L1: A1[p][q][r] = W1pad[k=8u+r][h], h = 32p + 8*(col>>2) + 4q + (col&3)
    // (A-row permutation chosen so L1's C/D layout IS L2's B-frag layout)
    bf16x8 A1[4][2];
#pragma unroll
    for (int p = 0; p < 4; ++p)
#pragma unroll
        for (int q = 0; q < 2; ++q) {
            const int h = 32 * p + 8 * (col >> 2) + 4 * q + (col & 3);
#pragma unroll
            for (int r = 0; r < 8; ++r) {
                const int k = 8 * u + r;
                float w = 0.0f;
                if (k < 6)       w = W1[k * HH + h];
                else if (k == 6) w = b1[h];
                A1[p][q][r] = f2bf(w);
            }
        }

    // L2: A2[mt][p][r] = W2[h=32p+8u+r][n2=16mt+col]
    bf16x8 A2[4][4];
#pragma unroll
    for (int mt = 0; mt < 4; ++mt)
#pragma unroll
        for (int p = 0; p < 4; ++p) {
            const int n2 = 16 * mt + col;
#pragma unroll
            for (int r = 0; r < 8; ++r) {
                const int h = 32 * p + 8 * u + r;
                A2[mt][p][r] = f2bf(W2[h * H2 + n2]);
            }
        }

    // epilogue constants; b2 enters as the p=0 L2 MFMA C-in
    f32x4 cinit[4];
    float w3c[16];
#pragma unroll
    for (int mt = 0; mt < 4; ++mt)
#pragma unroll
        for (int q = 0; q < 4; ++q) {
            const int n2 = 16 * mt + 4 * u + q;
            cinit[mt][q]    = b2[n2];
            w3c[mt * 4 + q] = W3[n2];
        }
    const float b3v = b3[0];

#pragma unroll
    for (int p = 0; p < 4; ++p) { KEEPV(A1[p][0]); KEEPV(A1[p][1]); }
#pragma unroll
    for (int mt = 0; mt < 4; ++mt)
#pragma unroll
        for (int p = 0; p < 4; ++p) KEEPV(A2[mt][p]);
#pragma unroll
    for (int mt = 0; mt < 4; ++mt) KEEPV(cinit[mt]);
#pragma unroll
    for (int q = 0; q < 16; ++q) KEEPF(w3c[q]);

    const int gw = blockIdx.x * 4 + wid;

    Pre cur, nxt;
    stage(gw, col, vertices, cur);       // gw < 4096 < NPAIR always

    for (int pt = gw; pt < NPAIR; pt += STRIDE) {
        const int ptn = pt + STRIDE;
        if (ptn < NPAIR) stage(ptn, col, vertices, nxt);  // issue-early

        const int tt0 = pt * 2;
        const int b   = tt0 / TPB;

        // ---- feature B-frags: 3 perms + const + 4 cndmask each ----
        bf16x8 bfv[2];
#pragma unroll
        for (int s = 0; s < 2; ++s) {
            u32x4 fb;
            fb[0] = pkbf(cur.f[s][0], cur.f[s][1]);
            fb[1] = pkbf(cur.f[s][2], cur.f[s][3]);
            fb[2] = pkbf(cur.f[s][4], cur.f[s][5]);
            fb[3] = 0x00003F80u;                 // bf16(1.0) in k=6, 0 in k=7
            if (u != 0) { fb[0] = 0; fb[1] = 0; fb[2] = 0; fb[3] = 0; }
            bfv[s] = __builtin_bit_cast(bf16x8, fb);
        }

        f32x4 d2[2][4];

        // ---- p = 0: b2 rides in as the accumulator init ----
#pragma unroll
        for (int s = 0; s < 2; ++s) {
            f32x4 dA = __builtin_amdgcn_mfma_f32_16x16x32_bf16(A1[0][0], bfv[s], zero4, 0, 0, 0);
            f32x4 dB = __builtin_amdgcn_mfma_f32_16x16x32_bf16(A1[0][1], bfv[s], zero4, 0, 0, 0);
            bf16x8 Bh = relu_pack(dA, dB);
            d2[s][0] = __builtin_amdgcn_mfma_f32_16x16x32_bf16(A2[0][0], Bh, cinit[0], 0, 0, 0);
            d2[s][1] = __builtin_amdgcn_mfma_f32_16x16x32_bf16(A2[1][0], Bh, cinit[1], 0, 0, 0);
            d2[s][2] = __builtin_amdgcn_mfma_f32_16x16x32_bf16(A2[2][0], Bh, cinit[2], 0, 0, 0);
            d2[s][3] = __builtin_amdgcn_mfma_f32_16x16x32_bf16(A2[3][0], Bh, cinit[3], 0, 0, 0);
        }

        // ---- p = 1..3 ----
#pragma unroll
        for (int p = 1; p < 4; ++p) {
#pragma unroll
            for (int s = 0; s < 2; ++s) {
                f32x4 dA = __builtin_amdgcn_mfma_f32_16x16x32_bf16(A1[p][0], bfv[s], zero4, 0, 0, 0);
                f32x4 dB = __builtin_amdgcn_mfma_f32_16x16x32_bf16(A1[p][1], bfv[s], zero4, 0, 0, 0);
                bf16x8 Bh = relu_pack(dA, dB);
                d2[s][0] = __builtin_amdgcn_mfma_f32_16x16x32_bf16(A2[0][p], Bh, d2[s][0], 0, 0, 0);
                d2[s][1] = __builtin_amdgcn_mfma_f32_16x16x32_bf16(A2[1][p], Bh, d2[s][1], 0, 0, 0);
                d2[s][2] = __builtin_amdgcn_mfma_f32_16x16x32_bf16(A2[2][p], Bh, d2[s][2], 0, 0, 0);
                d2[s][3] = __builtin_amdgcn_mfma_f32_16x16x32_bf16(A2[3][p], Bh, d2[s][3], 0, 0, 0);
            }
        }

        // ---- layer 3 + sigmoid + store ----
#pragma unroll
        for (int s = 0; s < 2; ++s) {
            float acc = 0.f;
#pragma unroll
            for (int mt = 0; mt < 4; ++mt)
#pragma unroll
                for (int q = 0; q < 4; ++q)
                    acc = fmaf(fmaxf(d2[s][mt][q], 0.f), w3c[mt * 4 + q], acc);

            acc += __shfl_xor(acc, 16);
            acc += __shfl_xor(acc, 32);

            if (u == 0) {
                const float x = acc + b3v;
                const float prob = __builtin_amdgcn_rcpf(1.0f + __expf(-x));
                out[(tt0 + s) * 16 + col] = prob;
                if (b == 0) {
                    const int e = (tt0 - b * TPB) * 16 + s * 16 + col;
                    *(float2*)(&out[BE + 2 * e]) =
                        make_float2((float)cur.iv[s], (float)cur.jv[s]);
                }
            }
        }

        cur = nxt;
    }
}

extern "C" void kernel_launch(void* const* d_in, const int* in_sizes, int n_in,
                              void* d_out, int out_size, void* d_ws, size_t ws_size,
                              hipStream_t stream) {
    const float* vertices = (const float*)d_in[0];
    const float* W1 = (const float*)d_in[1];
    const float* b1 = (const float*)d_in[2];
    const float* W2 = (const float*)d_in[3];
    const float* b2 = (const float*)d_in[4];
    const float* W3 = (const float*)d_in[5];
    const float* b3 = (const float*)d_in[6];
    float* out = (float*)d_out;

    edge_mlp_mfma5<<<NBLK, NTHR, 0, stream>>>(vertices, W1, b1, W2, b2, W3, b3, out);
}